// Round 2
// baseline (709.740 us; speedup 1.0000x reference)
//
#include <hip/hip_runtime.h>

#define NP 131072   // points (= 2^17, label packs above bit 17)
#define DD 128      // dims (GEMM K)
#define KK 256      // clusters (GEMM N)
#define MAXIT 8
#define TOLSQ (1e-4f * 1e-4f)
#define POSB 256    // positions per k_sum block
#define UPIPE 8     // gather pipeline depth

typedef _Float16 half8 __attribute__((ext_vector_type(8)));
typedef float f32x4 __attribute__((ext_vector_type(4)));

// Async 16B global -> LDS DMA. ldsptr must be the WAVE-UNIFORM base; HW
// writes base + lane*16 (m97/m104 semantics). Our layouts are exactly
// lane-contiguous in fragment order.
__device__ __forceinline__ void async_copy16(const void* g, void* l) {
    __builtin_amdgcn_global_load_lds(
        (const __attribute__((address_space(1))) void*)g,
        (__attribute__((address_space(3))) void*)l, 16, 0, 0);
}

// ws re-poisoned 0xAA before every timed call — every field below is written
// before it is read on every kernel_launch.
struct Ws {
    float C[KK * DD];
    float newC[KK * DD];
    float cnorm[KK];
    float sums[KK * DD];       // per-cluster coordinate sums (atomic-flushed)
    float shiftsq;
    int done;
    int ilab[NP];              // labels
    int counts[KK];            // per-cluster sizes (exact, int)
    int cursor[KK];            // global reservation cursors (zeroed per iter)
    int ordlab[NP];            // cluster-sorted: point | (label<<17)
    // fp16 hi/lo planes, pre-swizzled into MFMA fragment order (16B aligned)
    alignas(16) _Float16 Csh[KK * DD];
    alignas(16) _Float16 Csl[KK * DD];
    alignas(16) _Float16 Xsh[(size_t)NP * DD];
    alignas(16) _Float16 Xsl[(size_t)NP * DD];
};

// C0 = X[init_idx]; zero done flag.  grid: KK x DD
__global__ void k_init(const float* __restrict__ X, const int* __restrict__ idx,
                       float* __restrict__ C, int* __restrict__ done) {
    int k = blockIdx.x, d = threadIdx.x;
    C[k * DD + d] = X[(size_t)idx[k] * DD + d];
    if (k == 0 && d == 0) *done = 0;
}

// Once per call: split X into fp16 hi/lo planes in A-fragment order.
// A-frag (16x16x32 f16): lane L of the wave owning 16-point group g16 at
// k-step ks holds X[g16*16 + (L&15)][ks*32 + (L>>4)*8 + j], j=0..7.
// Flat: Xs[(((g16*4)+ks)*64 + L)*8 + j].  grid: NP*DD/8/256 = 8192 blocks.
__global__ void k_split(const float* __restrict__ X, _Float16* __restrict__ Xh,
                        _Float16* __restrict__ Xl) {
    size_t idx = (size_t)blockIdx.x * 256 + threadIdx.x;  // one per 8 elems
    int lane = idx & 63;
    size_t g16k = idx >> 6;
    size_t point = (g16k >> 2) * 16 + (lane & 15);
    int dim0 = (int)(g16k & 3) * 32 + (lane >> 4) * 8;
    const f32x4* s4 = (const f32x4*)(X + point * DD + dim0);
    f32x4 a = s4[0], b = s4[1];
    half8 h, l;
#pragma unroll
    for (int j = 0; j < 4; j++) {
        _Float16 hi = (_Float16)a[j];
        h[j] = hi; l[j] = (_Float16)(a[j] - (float)hi);
    }
#pragma unroll
    for (int j = 0; j < 4; j++) {
        _Float16 hi = (_Float16)b[j];
        h[4 + j] = hi; l[4 + j] = (_Float16)(b[j] - (float)hi);
    }
    *(half8*)(Xh + idx * 8) = h;
    *(half8*)(Xl + idx * 8) = l;
}

// Initial prep: cnorm + hi/lo B-fragment planes for C0; zero counts/cursor.
// B-frag: lane L at (ks, cluster-tile ct) holds C[ct*16+(L&15)][ks*32+(L>>4)*8+j]
// -> flat ((ks*16+ct)*64 + L)*8 + j.  grid: KK x DD
__global__ void k_prep0(const float* __restrict__ C, float* __restrict__ cnorm,
                        _Float16* __restrict__ Ch, _Float16* __restrict__ Cl,
                        int* __restrict__ counts, int* __restrict__ cursor) {
    int k = blockIdx.x, d = threadIdx.x;
    float v = C[k * DD + d];
    _Float16 hi = (_Float16)v;
    int ct = k >> 4, l4 = k & 15, ks = d >> 5, q = (d >> 3) & 3, j = d & 7;
    size_t dst = ((size_t)(ks * 16 + ct) * 64 + (q * 16 + l4)) * 8 + j;
    Ch[dst] = hi;
    Cl[dst] = (_Float16)(v - (float)hi);
    __shared__ float red[DD];
    red[d] = v * v;
    __syncthreads();
    for (int s = DD / 2; s > 0; s >>= 1) {
        if (d < s) red[d] += red[d + s];
        __syncthreads();
    }
    if (d == 0) {
        cnorm[k] = red[0];
        counts[k] = 0;
        cursor[k] = 0;
    }
}

// MFMA assignment, PERSISTENT-B + CLUSTER-SPLIT version. The whole C matrix
// (both fp16 planes, 128 KB) is staged into LDS once per block. 1024 threads
// = 16 waves; wave w handles point-group (w&7) x cluster-HALF (w>>3):
// 32 points x 128 clusters -> acc[2][8] = 64 VGPRs, total ~110 -> fits the
// <=128 VGPR boundary -> 4 waves/SIMD (vs 2 before). Total LDS B-traffic per
// point is unchanged (each 2KB B read still serves 32 points); we double the
// latency hiding over the 10.3us LDS floor that the previous version sat 4x
// above. Cluster-half argmins merge through a 2KB LDS buffer (1 barrier).
// A-plane reads are duplicated (2 waves per point, 134MB from L3) - hidden
// by the added TLP.  LDS: 128KB B + 2KB merge + 1KB hist -> 1 block/CU.
// grid: NP/256 = 512 x 1024.
__global__ __launch_bounds__(1024, 4) void k_assign(
    const _Float16* __restrict__ Xh, const _Float16* __restrict__ Xl,
    const _Float16* __restrict__ Ch, const _Float16* __restrict__ Cl,
    const float* __restrict__ cnorm, float* __restrict__ outlab,
    int* __restrict__ ilab, int* __restrict__ counts,
    float* __restrict__ shiftsq) {
    __shared__ __align__(16) _Float16 B[2 * KK * DD];      // Bh (64KB) then Bl (64KB)
    __shared__ unsigned long long mbuf[8 * 4 * 2 * 4];     // [pgrp][g][pg][r]
    __shared__ int hist[KK];
    const int tid = threadIdx.x;
    const int wave = tid >> 6;
    const int lane = tid & 63;
    const int l4 = lane & 15, g = lane >> 4;
    const int pgrp = wave & 7;      // point-group within block
    const int half = wave >> 3;     // cluster half (0: ct 0-7, 1: ct 8-15)

    if (blockIdx.x == 0 && tid == 0) *shiftsq = 0.0f;
    if (tid < KK) hist[tid] = 0;

    // One-time persistent stage: linear copy, fragment order already correct.
    // 1024 threads x 16B x 4 rounds x 2 planes = 128 KB.
    char* const lds = (char*)B;
#pragma unroll
    for (int r = 0; r < 4; r++) {
        const int slot = r * 1024 + wave * 64;  // 16B units, wave-uniform base
        async_copy16(Ch + (size_t)(slot + lane) * 8, lds + (size_t)slot * 16);
        async_copy16(Cl + (size_t)(slot + lane) * 8,
                     lds + 65536 + (size_t)slot * 16);
    }
    __syncthreads();  // drains stage DMA; hist zero visible

    const int g16 = blockIdx.x * 16 + pgrp * 2;

    f32x4 acc[2][8];
#pragma unroll
    for (int pg = 0; pg < 2; pg++)
#pragma unroll
        for (int ct = 0; ct < 8; ct++) acc[pg][ct] = (f32x4){0.f, 0.f, 0.f, 0.f};

    // preload slice 0 A-frags
    size_t a0 = ((size_t)(g16 * 4 + 0) * 64 + lane) * 8;
    size_t a1 = ((size_t)((g16 + 1) * 4 + 0) * 64 + lane) * 8;
    half8 ah0 = *(const half8*)(Xh + a0);
    half8 al0 = *(const half8*)(Xl + a0);
    half8 ah1 = *(const half8*)(Xh + a1);
    half8 al1 = *(const half8*)(Xl + a1);

#pragma unroll 1
    for (int ks = 0; ks < 4; ks++) {
        // prefetch next slice's A-frags under this slice's MFMAs
        half8 nh0, nl0, nh1, nl1;
        if (ks < 3) {
            const size_t b0 = ((size_t)(g16 * 4 + ks + 1) * 64 + lane) * 8;
            const size_t b1 = ((size_t)((g16 + 1) * 4 + ks + 1) * 64 + lane) * 8;
            nh0 = *(const half8*)(Xh + b0);
            nl0 = *(const half8*)(Xl + b0);
            nh1 = *(const half8*)(Xh + b1);
            nl1 = *(const half8*)(Xl + b1);
        }

        char* const curh = lds + ks * 16384 + half * 8192;
        char* const curl = curh + 65536;
#pragma unroll
        for (int ct = 0; ct < 8; ct++) {
            half8 bh = *(const half8*)(curh + ct * 1024 + lane * 16);
            half8 bl = *(const half8*)(curl + ct * 1024 + lane * 16);
            acc[0][ct] = __builtin_amdgcn_mfma_f32_16x16x32_f16(al0, bh, acc[0][ct], 0, 0, 0);
            acc[0][ct] = __builtin_amdgcn_mfma_f32_16x16x32_f16(ah0, bl, acc[0][ct], 0, 0, 0);
            acc[0][ct] = __builtin_amdgcn_mfma_f32_16x16x32_f16(ah0, bh, acc[0][ct], 0, 0, 0);
            acc[1][ct] = __builtin_amdgcn_mfma_f32_16x16x32_f16(al1, bh, acc[1][ct], 0, 0, 0);
            acc[1][ct] = __builtin_amdgcn_mfma_f32_16x16x32_f16(ah1, bl, acc[1][ct], 0, 0, 0);
            acc[1][ct] = __builtin_amdgcn_mfma_f32_16x16x32_f16(ah1, bh, acc[1][ct], 0, 0, 0);
        }
        ah0 = nh0; al0 = nl0; ah1 = nh1; al1 = nl1;
    }

    // epilogue: per-wave argmin over its 128 clusters. cn loaded here (not in
    // the loop) to keep loop VGPR pressure under the 128 boundary.
    float cn[8];
#pragma unroll
    for (int ct = 0; ct < 8; ct++) cn[ct] = cnorm[(half * 8 + ct) * 16 + l4];

    // Packed argmin keys: (monotone(float) << 32) | cluster. NaN -> -inf so
    // NaN beats all finite values; low bits give np's first-index tie-break.
    unsigned long long best[2][4];
#pragma unroll
    for (int pg = 0; pg < 2; pg++)
#pragma unroll
        for (int r = 0; r < 4; r++) best[pg][r] = ~0ull;

#pragma unroll
    for (int pg = 0; pg < 2; pg++)
#pragma unroll
        for (int ct = 0; ct < 8; ct++)
#pragma unroll
            for (int r = 0; r < 4; r++) {
                float s = fmaf(-2.0f, acc[pg][ct][r], cn[ct]);
                if (__builtin_isnan(s)) s = -__builtin_inff();
                unsigned u = __float_as_uint(s);
                unsigned m = (u >> 31) ? ~u : (u ^ 0x80000000u);
                unsigned long long key =
                    ((unsigned long long)m << 32) |
                    (unsigned)((half * 8 + ct) * 16 + l4);
                if (key < best[pg][r]) best[pg][r] = key;
            }

    // reduce over the 16 cluster-column lanes (low 4 lane bits)
#pragma unroll
    for (int d = 1; d < 16; d <<= 1)
#pragma unroll
        for (int pg = 0; pg < 2; pg++)
#pragma unroll
            for (int r = 0; r < 4; r++) {
                unsigned long long o = __shfl_xor(best[pg][r], d, 64);
                if (o < best[pg][r]) best[pg][r] = o;
            }

    // cross-half merge: half 1 parks its keys in LDS, half 0 min-combines.
    if (half && l4 == 0) {
#pragma unroll
        for (int pg = 0; pg < 2; pg++)
#pragma unroll
            for (int r = 0; r < 4; r++)
                mbuf[((pgrp * 4 + g) * 2 + pg) * 4 + r] = best[pg][r];
    }
    __syncthreads();
    if (!half && l4 == 0) {
#pragma unroll
        for (int pg = 0; pg < 2; pg++)
#pragma unroll
            for (int r = 0; r < 4; r++) {
                unsigned long long o = mbuf[((pgrp * 4 + g) * 2 + pg) * 4 + r];
                unsigned long long k = (o < best[pg][r]) ? o : best[pg][r];
                int point = (g16 + pg) * 16 + g * 4 + r;
                int lbl = (int)(k & 0x1ff);
                outlab[point] = (float)lbl;
                ilab[point] = lbl;
                atomicAdd(&hist[lbl], 1);
            }
    }

    __syncthreads();  // all hist adds complete
    if (tid < KK) {
        int h = hist[tid];
        if (h) atomicAdd(&counts[tid], h);
    }
}

// Counting-sort scatter. Block = 512 points: LDS histogram, redundant prefix
// of global counts, ONE block-aggregated cursor reservation per cluster, then
// rank & write ordlab[pos] = p | (label<<17). Also zeroes sums for k_sum.
// grid: NP/512 = 256 blocks x 256 threads.
__global__ __launch_bounds__(256) void k_scatter(
    const int* __restrict__ ilab, const int* __restrict__ counts,
    int* __restrict__ cursor, int* __restrict__ ordlab,
    float* __restrict__ sums) {
    const int t = threadIdx.x;
    const int b = blockIdx.x;

    // zero sums slice: 256 blocks x 128 floats = KK*DD
    if (t < 128) sums[b * 128 + t] = 0.0f;

    __shared__ int hist[KK];
    __shared__ int pre[KK];
    __shared__ int gbase[KK];
    hist[t] = 0;
    int c = counts[t];
    pre[t] = c;
    __syncthreads();

    const int p0 = b * 512;
    const int la = ilab[p0 + t];
    const int lb = ilab[p0 + 256 + t];
    atomicAdd(&hist[la], 1);
    atomicAdd(&hist[lb], 1);

    // inclusive prefix of counts (Hillis-Steele)
#pragma unroll
    for (int d = 1; d < KK; d <<= 1) {
        int v = (t >= d) ? pre[t - d] : 0;
        __syncthreads();
        pre[t] += v;
        __syncthreads();
    }
    // after these syncs all hist atomics are complete
    int h = hist[t];
    int gb = (pre[t] - c) + (h ? atomicAdd(&cursor[t], h) : 0);
    gbase[t] = gb;
    __syncthreads();
    hist[t] = 0;  // reuse as intra-block rank cursor
    __syncthreads();

    int ra = atomicAdd(&hist[la], 1);
    ordlab[gbase[la] + ra] = (p0 + t) | (la << 17);
    int rb = atomicAdd(&hist[lb], 1);
    ordlab[gbase[lb] + rb] = (p0 + 256 + t) | (lb << 17);
}

// Streaming segmented sum over the cluster-sorted position list.
// Position-balanced (immune to cluster-size skew). Thread = (dim d, parity h);
// U-deep double-buffered row gathers; register accumulator flushed on label
// change (wave-uniform branch) via coalesced global atomicAdd — few per block.
// grid: NP/POSB = 512 blocks x 256 threads.
__global__ __launch_bounds__(256) void k_sum(
    const float* __restrict__ X, const int* __restrict__ ordlab,
    float* __restrict__ sums) {
    const int t = threadIdx.x;
    const int d = t & 127, h = t >> 7;

    __shared__ int sol[POSB];
    sol[t] = ordlab[blockIdx.x * POSB + t];
    __syncthreads();

    const int PP = POSB / 2;  // positions per parity
    float xv[UPIPE], xn[UPIPE];
#pragma unroll
    for (int u = 0; u < UPIPE; u++)
        xv[u] = X[(size_t)(sol[2 * u + h] & 0x1ffff) * DD + d];

    float acc = 0.0f;
    int cur = sol[h] >> 17;

    for (int jb = 0; jb < PP; jb += UPIPE) {
        // issue next batch's gathers (tail clamped to a harmless valid index)
#pragma unroll
        for (int u = 0; u < UPIPE; u++) {
            int nj = jb + u + UPIPE;
            int o = sol[2 * (nj < PP ? nj : PP - 1) + h];
            xn[u] = X[(size_t)(o & 0x1ffff) * DD + d];
        }
        // consume current batch
#pragma unroll
        for (int u = 0; u < UPIPE; u++) {
            int l = sol[2 * (jb + u) + h] >> 17;
            if (l != cur) {
                atomicAdd(&sums[cur * DD + d], acc);
                acc = 0.0f;
                cur = l;
            }
            acc += xv[u];
        }
#pragma unroll
        for (int u = 0; u < UPIPE; u++) xv[u] = xn[u];
    }
    atomicAdd(&sums[cur * DD + d], acc);
}

// newC = sums/counts (0/0 -> NaN, matching jnp); shift^2 block-reduced,
// one atomic per block.  grid: KK*DD/256 x 256
__global__ void k_reduce(const float* __restrict__ sums, const int* __restrict__ counts,
                         const float* __restrict__ C, float* __restrict__ newC,
                         float* __restrict__ shiftsq) {
    const int g = blockIdx.x * 256 + threadIdx.x;
    const int k = g >> 7;
    const int t = threadIdx.x;

    float nc = sums[g] / (float)counts[k];
    newC[g] = nc;
    float diff = nc - C[g];

    __shared__ float red[256];
    red[t] = diff * diff;
    __syncthreads();
    for (int st = 128; st > 0; st >>= 1) {
        if (t < st) red[t] += red[t + st];
        __syncthreads();
    }
    if (t == 0) atomicAdd(shiftsq, red[0]);
}

// Fused convergence check + centroid update + next-iter prep (cnorm + hi/lo
// planes) + zero counts/cursor. NaN shiftsq -> not converged (jnp match).
// Benign done race: all blocks compute the same nd.  grid: KK/2 x 256.
__global__ void k_upprep(const float* __restrict__ newC, float* __restrict__ C,
                         const float* __restrict__ shiftsq, int* __restrict__ done,
                         float* __restrict__ cnorm, _Float16* __restrict__ Ch,
                         _Float16* __restrict__ Cl, int* __restrict__ counts,
                         int* __restrict__ cursor) {
    const int t = threadIdx.x;
    const int k = blockIdx.x * 2 + (t >> 7);
    const int d = t & 127;
    float ss = *shiftsq;
    int nd = (*done != 0) || (ss < TOLSQ);
    float v = nd ? C[k * DD + d] : newC[k * DD + d];
    C[k * DD + d] = v;
    if (blockIdx.x == 0 && t == 0 && nd) *done = 1;
    if (d == 0) {
        counts[k] = 0;
        cursor[k] = 0;
    }

    _Float16 hi = (_Float16)v;
    int ct = k >> 4, l4 = k & 15, ks = d >> 5, q = (d >> 3) & 3, j = d & 7;
    size_t dst = ((size_t)(ks * 16 + ct) * 64 + (q * 16 + l4)) * 8 + j;
    Ch[dst] = hi;
    Cl[dst] = (_Float16)(v - (float)hi);

    __shared__ float red[256];
    red[t] = v * v;
    __syncthreads();
    for (int s = 64; s > 0; s >>= 1) {
        if ((t & 127) < s) red[t] += red[t + s];
        __syncthreads();
    }
    if (d == 0) cnorm[k] = red[t];
}

__global__ void k_final(const float* __restrict__ C, float* __restrict__ out) {
    int i = blockIdx.x * 256 + threadIdx.x;
    out[i] = C[i];
}

extern "C" void kernel_launch(void* const* d_in, const int* in_sizes, int n_in,
                              void* d_out, int out_size, void* d_ws, size_t ws_size,
                              hipStream_t stream) {
    const float* X = (const float*)d_in[0];
    const int* idx = (const int*)d_in[1];
    float* out = (float*)d_out;
    Ws* w = (Ws*)d_ws;

    k_init<<<KK, DD, 0, stream>>>(X, idx, w->C, &w->done);
    k_split<<<(int)((size_t)NP * DD / 8 / 256), 256, 0, stream>>>(X, w->Xsh, w->Xsl);
    k_prep0<<<KK, DD, 0, stream>>>(w->C, w->cnorm, w->Csh, w->Csl, w->counts, w->cursor);

    for (int it = 0; it < MAXIT; it++) {
        k_assign<<<NP / 256, 1024, 0, stream>>>(w->Xsh, w->Xsl, w->Csh, w->Csl,
                                                w->cnorm, out, w->ilab, w->counts,
                                                &w->shiftsq);
        k_scatter<<<NP / 512, 256, 0, stream>>>(w->ilab, w->counts, w->cursor,
                                                w->ordlab, w->sums);
        k_sum<<<NP / POSB, 256, 0, stream>>>(X, w->ordlab, w->sums);
        k_reduce<<<KK * DD / 256, 256, 0, stream>>>(w->sums, w->counts, w->C,
                                                    w->newC, &w->shiftsq);
        k_upprep<<<KK / 2, 256, 0, stream>>>(w->newC, w->C, &w->shiftsq, &w->done,
                                             w->cnorm, w->Csh, w->Csl, w->counts,
                                             w->cursor);
    }

    k_final<<<KK * DD / 256, 256, 0, stream>>>(w->C, out + NP);
}

// Round 3
// 631.763 us; speedup vs baseline: 1.1234x; 1.1234x over previous
//
#include <hip/hip_runtime.h>

#define NP 131072   // points (= 2^17, label packs above bit 17)
#define DD 128      // dims (GEMM K)
#define KK 256      // clusters (GEMM N)
#define MAXIT 8
#define TOLSQ (1e-4f * 1e-4f)
#define POSB 256    // positions per k_sum block
#define UPIPE 8     // gather pipeline depth

typedef _Float16 half8 __attribute__((ext_vector_type(8)));
typedef float f32x4 __attribute__((ext_vector_type(4)));

// ws re-poisoned 0xAA before every timed call — every field below is written
// before it is read on every kernel_launch.
struct Ws {
    float C[KK * DD];
    float newC[KK * DD];
    float cnorm[KK];
    float sums[KK * DD];       // per-cluster coordinate sums (atomic-flushed)
    float shiftsq;
    int done;
    int ilab[NP];              // labels
    int counts[KK];            // per-cluster sizes (exact, int)
    int cursor[KK];            // global reservation cursors (zeroed per iter)
    int ordlab[NP];            // cluster-sorted: point | (label<<17)
    // fp16 hi/lo planes, pre-swizzled into MFMA fragment order (16B aligned)
    alignas(16) _Float16 Csh[KK * DD];
    alignas(16) _Float16 Csl[KK * DD];
    alignas(16) _Float16 Xsh[(size_t)NP * DD];
    alignas(16) _Float16 Xsl[(size_t)NP * DD];
};

// C0 = X[init_idx]; zero done flag.  grid: KK x DD
__global__ void k_init(const float* __restrict__ X, const int* __restrict__ idx,
                       float* __restrict__ C, int* __restrict__ done) {
    int k = blockIdx.x, d = threadIdx.x;
    C[k * DD + d] = X[(size_t)idx[k] * DD + d];
    if (k == 0 && d == 0) *done = 0;
}

// Once per call: split X into fp16 hi/lo planes in A-fragment order.
// A-frag (16x16x32 f16): lane L of the wave owning 16-point group g16 at
// k-step ks holds X[g16*16 + (L&15)][ks*32 + (L>>4)*8 + j], j=0..7.
// Flat: Xs[(((g16*4)+ks)*64 + L)*8 + j].  grid: NP*DD/8/256 = 8192 blocks.
__global__ void k_split(const float* __restrict__ X, _Float16* __restrict__ Xh,
                        _Float16* __restrict__ Xl) {
    size_t idx = (size_t)blockIdx.x * 256 + threadIdx.x;  // one per 8 elems
    int lane = idx & 63;
    size_t g16k = idx >> 6;
    size_t point = (g16k >> 2) * 16 + (lane & 15);
    int dim0 = (int)(g16k & 3) * 32 + (lane >> 4) * 8;
    const f32x4* s4 = (const f32x4*)(X + point * DD + dim0);
    f32x4 a = s4[0], b = s4[1];
    half8 h, l;
#pragma unroll
    for (int j = 0; j < 4; j++) {
        _Float16 hi = (_Float16)a[j];
        h[j] = hi; l[j] = (_Float16)(a[j] - (float)hi);
    }
#pragma unroll
    for (int j = 0; j < 4; j++) {
        _Float16 hi = (_Float16)b[j];
        h[4 + j] = hi; l[4 + j] = (_Float16)(b[j] - (float)hi);
    }
    *(half8*)(Xh + idx * 8) = h;
    *(half8*)(Xl + idx * 8) = l;
}

// Initial prep: cnorm + hi/lo B-fragment planes for C0; zero counts/cursor.
// B-frag: lane L at (ks, cluster-tile ct) holds C[ct*16+(L&15)][ks*32+(L>>4)*8+j]
// -> flat ((ks*16+ct)*64 + L)*8 + j.  grid: KK x DD
__global__ void k_prep0(const float* __restrict__ C, float* __restrict__ cnorm,
                        _Float16* __restrict__ Ch, _Float16* __restrict__ Cl,
                        int* __restrict__ counts, int* __restrict__ cursor) {
    int k = blockIdx.x, d = threadIdx.x;
    float v = C[k * DD + d];
    _Float16 hi = (_Float16)v;
    int ct = k >> 4, l4 = k & 15, ks = d >> 5, q = (d >> 3) & 3, j = d & 7;
    size_t dst = ((size_t)(ks * 16 + ct) * 64 + (q * 16 + l4)) * 8 + j;
    Ch[dst] = hi;
    Cl[dst] = (_Float16)(v - (float)hi);
    __shared__ float red[DD];
    red[d] = v * v;
    __syncthreads();
    for (int s = DD / 2; s > 0; s >>= 1) {
        if (d < s) red[d] += red[d + s];
        __syncthreads();
    }
    if (d == 0) {
        cnorm[k] = red[0];
        counts[k] = 0;
        cursor[k] = 0;
    }
}

// MFMA assignment, B-IN-REGISTERS version. Discriminating experiment after
// three structurally different LDS-staged schedules all pinned at 47-49us /
// 20% MfmaUtil: remove LDS from the operand path entirely. 8 waves = 2
// point-groups x 4 cluster-quarters; each wave holds its B quarter (4 ct x
// 4 ks x hi/lo = 32 half8 = 128 VGPR) permanently in registers, loaded from
// global once. Main loop: 8 rounds x 4 ks-steps of [4 prefetched A-loads +
// 24 MFMAs]; dependent acc chains spaced 8 issues apart; ZERO ds_reads,
// ZERO barriers. Cross-quarter argmin merge via plain u64 writes to
// mbuf[4][512] + one end barrier. A-frags are read by both pgrp-waves of
// 4 quarters in the same CU -> L1/L2 hot. ~195 VGPR + 32 AGPR -> 2 waves/
// SIMD, sufficient: only stall source is a 1-step-ahead prefetch (~200-300
// cyc L2) under ~930 cyc of own MFMA issue.  LDS: 17.4 KB.
// grid: NP/512 = 256 x 512.
__global__ __launch_bounds__(512, 2) void k_assign(
    const _Float16* __restrict__ Xh, const _Float16* __restrict__ Xl,
    const _Float16* __restrict__ Ch, const _Float16* __restrict__ Cl,
    const float* __restrict__ cnorm, float* __restrict__ outlab,
    int* __restrict__ ilab, int* __restrict__ counts,
    float* __restrict__ shiftsq) {
    __shared__ unsigned long long mbuf[4][512];  // [quarter][local point]
    __shared__ int hist[KK];
    const int tid = threadIdx.x;
    const int wave = tid >> 6;
    const int lane = tid & 63;
    const int l4 = lane & 15, g = lane >> 4;
    const int pgrp = wave >> 2;   // point-group pair (0..1)
    const int q = wave & 3;       // cluster quarter (ct q*4 .. q*4+3)

    if (blockIdx.x == 0 && tid == 0) *shiftsq = 0.0f;
    if (tid < KK) hist[tid] = 0;

    // B quarter into registers, permanent. Fragment layout matches k_prep0:
    // flat ((ks*16 + ct)*64 + lane)*8, 16B/lane coalesced.
    half8 Bh[4][4], Bl[4][4];
#pragma unroll
    for (int ks = 0; ks < 4; ks++)
#pragma unroll
        for (int c = 0; c < 4; c++) {
            size_t off = ((size_t)(ks * 16 + q * 4 + c) * 64 + lane) * 8;
            Bh[ks][c] = *(const half8*)(Ch + off);
            Bl[ks][c] = *(const half8*)(Cl + off);
        }

    float cn[4];
#pragma unroll
    for (int c = 0; c < 4; c++) cn[c] = cnorm[(q * 4 + c) * 16 + l4];

    // prologue: A-frags for (round 0, ks 0)
    const int gb = blockIdx.x * 32 + pgrp * 2;
    size_t a0 = ((size_t)(gb * 4) * 64 + lane) * 8;
    size_t a1 = ((size_t)((gb + 1) * 4) * 64 + lane) * 8;
    half8 ah0 = *(const half8*)(Xh + a0), al0 = *(const half8*)(Xl + a0);
    half8 ah1 = *(const half8*)(Xh + a1), al1 = *(const half8*)(Xl + a1);

#pragma unroll 1
    for (int r = 0; r < 8; r++) {
        f32x4 acc[2][4];
#pragma unroll
        for (int pg = 0; pg < 2; pg++)
#pragma unroll
            for (int c = 0; c < 4; c++) acc[pg][c] = (f32x4){0.f, 0.f, 0.f, 0.f};

#pragma unroll
        for (int ks = 0; ks < 4; ks++) {
            // prefetch next flat step's A (clamped re-load on the very last)
            int ns = r * 4 + ks + 1;
            ns = ns > 31 ? 31 : ns;
            const int ng16 = blockIdx.x * 32 + (ns >> 2) * 4 + pgrp * 2;
            const int nks = ns & 3;
            const size_t b0 = ((size_t)(ng16 * 4 + nks) * 64 + lane) * 8;
            const size_t b1 = ((size_t)((ng16 + 1) * 4 + nks) * 64 + lane) * 8;
            half8 nh0 = *(const half8*)(Xh + b0), nl0 = *(const half8*)(Xl + b0);
            half8 nh1 = *(const half8*)(Xh + b1), nl1 = *(const half8*)(Xl + b1);

            // 24 MFMAs; dependent chains (same acc) are 8 issues apart.
#pragma unroll
            for (int c = 0; c < 4; c++) {
                acc[0][c] = __builtin_amdgcn_mfma_f32_16x16x32_f16(al0, Bh[ks][c], acc[0][c], 0, 0, 0);
                acc[1][c] = __builtin_amdgcn_mfma_f32_16x16x32_f16(al1, Bh[ks][c], acc[1][c], 0, 0, 0);
            }
#pragma unroll
            for (int c = 0; c < 4; c++) {
                acc[0][c] = __builtin_amdgcn_mfma_f32_16x16x32_f16(ah0, Bl[ks][c], acc[0][c], 0, 0, 0);
                acc[1][c] = __builtin_amdgcn_mfma_f32_16x16x32_f16(ah1, Bl[ks][c], acc[1][c], 0, 0, 0);
            }
#pragma unroll
            for (int c = 0; c < 4; c++) {
                acc[0][c] = __builtin_amdgcn_mfma_f32_16x16x32_f16(ah0, Bh[ks][c], acc[0][c], 0, 0, 0);
                acc[1][c] = __builtin_amdgcn_mfma_f32_16x16x32_f16(ah1, Bh[ks][c], acc[1][c], 0, 0, 0);
            }
            ah0 = nh0; al0 = nl0; ah1 = nh1; al1 = nl1;
        }

        // Round epilogue: packed argmin over this wave's 64 clusters.
        // Key = (monotone(float) << 32) | cluster; NaN -> -inf beats all.
        unsigned long long best[2][4];
#pragma unroll
        for (int pg = 0; pg < 2; pg++)
#pragma unroll
            for (int rr = 0; rr < 4; rr++) best[pg][rr] = ~0ull;

#pragma unroll
        for (int pg = 0; pg < 2; pg++)
#pragma unroll
            for (int c = 0; c < 4; c++)
#pragma unroll
                for (int rr = 0; rr < 4; rr++) {
                    float s = fmaf(-2.0f, acc[pg][c][rr], cn[c]);
                    if (__builtin_isnan(s)) s = -__builtin_inff();
                    unsigned u = __float_as_uint(s);
                    unsigned m = (u >> 31) ? ~u : (u ^ 0x80000000u);
                    unsigned long long key =
                        ((unsigned long long)m << 32) |
                        (unsigned)((q * 4 + c) * 16 + l4);
                    if (key < best[pg][rr]) best[pg][rr] = key;
                }

        // reduce over the 16 cluster-column lanes (low 4 lane bits)
#pragma unroll
        for (int d = 1; d < 16; d <<= 1)
#pragma unroll
            for (int pg = 0; pg < 2; pg++)
#pragma unroll
                for (int rr = 0; rr < 4; rr++) {
                    unsigned long long o = __shfl_xor(best[pg][rr], d, 64);
                    if (o < best[pg][rr]) best[pg][rr] = o;
                }

        if (l4 == 0) {
#pragma unroll
            for (int pg = 0; pg < 2; pg++)
#pragma unroll
                for (int rr = 0; rr < 4; rr++) {
                    int pl = (r * 4 + pgrp * 2 + pg) * 16 + g * 4 + rr;
                    mbuf[q][pl] = best[pg][rr];
                }
        }
    }

    __syncthreads();  // all mbuf writes + hist zero visible
    {
        unsigned long long k0 = mbuf[0][tid], k1 = mbuf[1][tid];
        unsigned long long k2 = mbuf[2][tid], k3 = mbuf[3][tid];
        unsigned long long ka = k0 < k1 ? k0 : k1;
        unsigned long long kb = k2 < k3 ? k2 : k3;
        unsigned long long k = ka < kb ? ka : kb;
        int point = blockIdx.x * 512 + tid;
        int lbl = (int)(k & 0x1ff);
        outlab[point] = (float)lbl;
        ilab[point] = lbl;
        atomicAdd(&hist[lbl], 1);
    }
    __syncthreads();  // all hist adds complete
    if (tid < KK) {
        int h = hist[tid];
        if (h) atomicAdd(&counts[tid], h);
    }
}

// Counting-sort scatter. Block = 512 points: LDS histogram, redundant prefix
// of global counts, ONE block-aggregated cursor reservation per cluster, then
// rank & write ordlab[pos] = p | (label<<17). Also zeroes sums for k_sum.
// grid: NP/512 = 256 blocks x 256 threads.
__global__ __launch_bounds__(256) void k_scatter(
    const int* __restrict__ ilab, const int* __restrict__ counts,
    int* __restrict__ cursor, int* __restrict__ ordlab,
    float* __restrict__ sums) {
    const int t = threadIdx.x;
    const int b = blockIdx.x;

    // zero sums slice: 256 blocks x 128 floats = KK*DD
    if (t < 128) sums[b * 128 + t] = 0.0f;

    __shared__ int hist[KK];
    __shared__ int pre[KK];
    __shared__ int gbase[KK];
    hist[t] = 0;
    int c = counts[t];
    pre[t] = c;
    __syncthreads();

    const int p0 = b * 512;
    const int la = ilab[p0 + t];
    const int lb = ilab[p0 + 256 + t];
    atomicAdd(&hist[la], 1);
    atomicAdd(&hist[lb], 1);

    // inclusive prefix of counts (Hillis-Steele)
#pragma unroll
    for (int d = 1; d < KK; d <<= 1) {
        int v = (t >= d) ? pre[t - d] : 0;
        __syncthreads();
        pre[t] += v;
        __syncthreads();
    }
    // after these syncs all hist atomics are complete
    int h = hist[t];
    int gb = (pre[t] - c) + (h ? atomicAdd(&cursor[t], h) : 0);
    gbase[t] = gb;
    __syncthreads();
    hist[t] = 0;  // reuse as intra-block rank cursor
    __syncthreads();

    int ra = atomicAdd(&hist[la], 1);
    ordlab[gbase[la] + ra] = (p0 + t) | (la << 17);
    int rb = atomicAdd(&hist[lb], 1);
    ordlab[gbase[lb] + rb] = (p0 + 256 + t) | (lb << 17);
}

// Streaming segmented sum over the cluster-sorted position list.
// Position-balanced (immune to cluster-size skew). Thread = (dim d, parity h);
// U-deep double-buffered row gathers; register accumulator flushed on label
// change (wave-uniform branch) via coalesced global atomicAdd — few per block.
// grid: NP/POSB = 512 blocks x 256 threads.
__global__ __launch_bounds__(256) void k_sum(
    const float* __restrict__ X, const int* __restrict__ ordlab,
    float* __restrict__ sums) {
    const int t = threadIdx.x;
    const int d = t & 127, h = t >> 7;

    __shared__ int sol[POSB];
    sol[t] = ordlab[blockIdx.x * POSB + t];
    __syncthreads();

    const int PP = POSB / 2;  // positions per parity
    float xv[UPIPE], xn[UPIPE];
#pragma unroll
    for (int u = 0; u < UPIPE; u++)
        xv[u] = X[(size_t)(sol[2 * u + h] & 0x1ffff) * DD + d];

    float acc = 0.0f;
    int cur = sol[h] >> 17;

    for (int jb = 0; jb < PP; jb += UPIPE) {
        // issue next batch's gathers (tail clamped to a harmless valid index)
#pragma unroll
        for (int u = 0; u < UPIPE; u++) {
            int nj = jb + u + UPIPE;
            int o = sol[2 * (nj < PP ? nj : PP - 1) + h];
            xn[u] = X[(size_t)(o & 0x1ffff) * DD + d];
        }
        // consume current batch
#pragma unroll
        for (int u = 0; u < UPIPE; u++) {
            int l = sol[2 * (jb + u) + h] >> 17;
            if (l != cur) {
                atomicAdd(&sums[cur * DD + d], acc);
                acc = 0.0f;
                cur = l;
            }
            acc += xv[u];
        }
#pragma unroll
        for (int u = 0; u < UPIPE; u++) xv[u] = xn[u];
    }
    atomicAdd(&sums[cur * DD + d], acc);
}

// newC = sums/counts (0/0 -> NaN, matching jnp); shift^2 block-reduced,
// one atomic per block.  grid: KK*DD/256 x 256
__global__ void k_reduce(const float* __restrict__ sums, const int* __restrict__ counts,
                         const float* __restrict__ C, float* __restrict__ newC,
                         float* __restrict__ shiftsq) {
    const int g = blockIdx.x * 256 + threadIdx.x;
    const int k = g >> 7;
    const int t = threadIdx.x;

    float nc = sums[g] / (float)counts[k];
    newC[g] = nc;
    float diff = nc - C[g];

    __shared__ float red[256];
    red[t] = diff * diff;
    __syncthreads();
    for (int st = 128; st > 0; st >>= 1) {
        if (t < st) red[t] += red[t + st];
        __syncthreads();
    }
    if (t == 0) atomicAdd(shiftsq, red[0]);
}

// Fused convergence check + centroid update + next-iter prep (cnorm + hi/lo
// planes) + zero counts/cursor. NaN shiftsq -> not converged (jnp match).
// Benign done race: all blocks compute the same nd.  grid: KK/2 x 256.
__global__ void k_upprep(const float* __restrict__ newC, float* __restrict__ C,
                         const float* __restrict__ shiftsq, int* __restrict__ done,
                         float* __restrict__ cnorm, _Float16* __restrict__ Ch,
                         _Float16* __restrict__ Cl, int* __restrict__ counts,
                         int* __restrict__ cursor) {
    const int t = threadIdx.x;
    const int k = blockIdx.x * 2 + (t >> 7);
    const int d = t & 127;
    float ss = *shiftsq;
    int nd = (*done != 0) || (ss < TOLSQ);
    float v = nd ? C[k * DD + d] : newC[k * DD + d];
    C[k * DD + d] = v;
    if (blockIdx.x == 0 && t == 0 && nd) *done = 1;
    if (d == 0) {
        counts[k] = 0;
        cursor[k] = 0;
    }

    _Float16 hi = (_Float16)v;
    int ct = k >> 4, l4 = k & 15, ks = d >> 5, q = (d >> 3) & 3, j = d & 7;
    size_t dst = ((size_t)(ks * 16 + ct) * 64 + (q * 16 + l4)) * 8 + j;
    Ch[dst] = hi;
    Cl[dst] = (_Float16)(v - (float)hi);

    __shared__ float red[256];
    red[t] = v * v;
    __syncthreads();
    for (int s = 64; s > 0; s >>= 1) {
        if ((t & 127) < s) red[t] += red[t + s];
        __syncthreads();
    }
    if (d == 0) cnorm[k] = red[t];
}

__global__ void k_final(const float* __restrict__ C, float* __restrict__ out) {
    int i = blockIdx.x * 256 + threadIdx.x;
    out[i] = C[i];
}

extern "C" void kernel_launch(void* const* d_in, const int* in_sizes, int n_in,
                              void* d_out, int out_size, void* d_ws, size_t ws_size,
                              hipStream_t stream) {
    const float* X = (const float*)d_in[0];
    const int* idx = (const int*)d_in[1];
    float* out = (float*)d_out;
    Ws* w = (Ws*)d_ws;

    k_init<<<KK, DD, 0, stream>>>(X, idx, w->C, &w->done);
    k_split<<<(int)((size_t)NP * DD / 8 / 256), 256, 0, stream>>>(X, w->Xsh, w->Xsl);
    k_prep0<<<KK, DD, 0, stream>>>(w->C, w->cnorm, w->Csh, w->Csl, w->counts, w->cursor);

    for (int it = 0; it < MAXIT; it++) {
        k_assign<<<NP / 512, 512, 0, stream>>>(w->Xsh, w->Xsl, w->Csh, w->Csl,
                                               w->cnorm, out, w->ilab, w->counts,
                                               &w->shiftsq);
        k_scatter<<<NP / 512, 256, 0, stream>>>(w->ilab, w->counts, w->cursor,
                                                w->ordlab, w->sums);
        k_sum<<<NP / POSB, 256, 0, stream>>>(X, w->ordlab, w->sums);
        k_reduce<<<KK * DD / 256, 256, 0, stream>>>(w->sums, w->counts, w->C,
                                                    w->newC, &w->shiftsq);
        k_upprep<<<KK / 2, 256, 0, stream>>>(w->newC, w->C, &w->shiftsq, &w->done,
                                             w->cnorm, w->Csh, w->Csl, w->counts,
                                             w->cursor);
    }

    k_final<<<KK * DD / 256, 256, 0, stream>>>(w->C, out + NP);
}